// Round 7
// baseline (307.591 us; speedup 1.0000x reference)
//
#include <hip/hip_runtime.h>

// MHA: B=4 S=2048 D=1024 H=16 DH=64. Full bf16-MFMA pipeline (fp32 accum).

#define Bn  4
#define Sn  2048
#define Dn  1024
#define Hn  16
#define DHn 64
#define Mn  (Bn*Sn)          // 8192 rows
#define LDKV 72              // attn V LDS row stride (ushorts)

typedef unsigned short u16;
typedef __attribute__((ext_vector_type(8))) short short8;   // 8 x bf16 (4 VGPRs)
typedef __attribute__((ext_vector_type(4))) short short4v;  // 4 x bf16 (2 VGPRs)
typedef __attribute__((ext_vector_type(4))) float f32x4;    // MFMA C/D frag
typedef __attribute__((ext_vector_type(4))) unsigned int uint4v;

__device__ __forceinline__ u16 f2bf(float f) {
  unsigned u = __float_as_uint(f);
  return (u16)((u + 0x7FFFu + ((u >> 16) & 1u)) >> 16);   // RNE
}

// async 16B/lane global->LDS DMA; lds dest = wave-uniform base + lane*16
__device__ __forceinline__ void async16(const void* g, void* l) {
  __builtin_amdgcn_global_load_lds(
      (const __attribute__((address_space(1))) void*)g,
      (__attribute__((address_space(3))) void*)l, 16, 0, 0);
}

// pack 2 fp32 -> 2 bf16 (truncation) in one v_perm_b32
__device__ __forceinline__ unsigned pk2(float a, float b) {
  return __builtin_amdgcn_perm(__float_as_uint(b), __float_as_uint(a), 0x07060302u);
}

// ---------------- convert: x (f32) -> xb (bf16) ----------------
__global__ __launch_bounds__(256) void k_convert_x(
    const float4* __restrict__ x, ushort4* __restrict__ xb, int n4) {
  int i = blockIdx.x * 256 + threadIdx.x;
  if (i < n4) {
    float4 f = x[i];
    ushort4 o;
    o.x = f2bf(f.x); o.y = f2bf(f.y); o.z = f2bf(f.z); o.w = f2bf(f.w);
    xb[i] = o;
  }
}

// ---- convert+transpose weights to [N][K] bf16 via LDS 64x64 tiles ----
__global__ __launch_bounds__(256) void k_convert_w(
    const float* __restrict__ Wq, const float* __restrict__ Wk,
    const float* __restrict__ Wv, const float* __restrict__ Wo,
    u16* __restrict__ WqT, u16* __restrict__ WkT,
    u16* __restrict__ WvT, u16* __restrict__ WoT) {
  __shared__ float t[64][65];
  const int bid = blockIdx.x;          // 0..1023
  const int wsel = bid >> 8;           // 0..3
  const int idx = bid & 255;
  const int tid = threadIdx.x;
  const int c = tid & 63;
  const int r4 = tid >> 6;             // 0..3

  if (wsel < 3) {
    const float* W = (wsel == 0) ? Wq : (wsel == 1) ? Wk : Wv;
    u16* T = (wsel == 0) ? WqT : (wsel == 1) ? WkT : WvT;
    const int h = idx >> 4;
    const int d0 = (idx & 15) * 64;
    const float* src = W + (size_t)h * (Dn * DHn) + (size_t)d0 * DHn;
#pragma unroll
    for (int r = 0; r < 16; r++) {
      int row = r * 4 + r4;
      t[row][c] = src[row * DHn + c];
    }
    __syncthreads();
    u16* dst = T + (size_t)(h * 64) * Dn + d0;
#pragma unroll
    for (int r = 0; r < 16; r++) {
      int erow = r * 4 + r4;
      dst[(size_t)erow * Dn + c] = f2bf(t[c][erow]);
    }
  } else {
    const int n0 = (idx >> 4) * 64;
    const int d0 = (idx & 15) * 64;
#pragma unroll
    for (int r = 0; r < 16; r++) {
      int row = r * 4 + r4;
      t[row][c] = Wo[(size_t)(d0 + row) * Dn + n0 + c];
    }
    __syncthreads();
#pragma unroll
    for (int r = 0; r < 16; r++) {
      int nrow = r * 4 + r4;
      WoT[(size_t)(n0 + nrow) * Dn + d0 + c] = f2bf(t[c][nrow]);
    }
  }
}

// ---------------- QKV projection GEMM: 512 thr / 8 waves (unchanged R6) ----------------
template<int SWAP>
__global__ __launch_bounds__(512) void k_gemm_qkv(
    const u16* __restrict__ A, const u16* __restrict__ B0T,
    const u16* __restrict__ B1T, const float* __restrict__ bias0,
    const float* __restrict__ bias1, u16* __restrict__ out0,
    u16* __restrict__ out1) {
  const int z = blockIdx.z;
  const u16* BT = z ? B1T : B0T;
  const float* bias = z ? bias1 : bias0;
  u16* dst = z ? out1 : out0;
  const int tile_m = blockIdx.x * 128;
  const int tile_n = blockIdx.y * 128;
  const int K = Dn;

  __shared__ u16 As[128 * 64];
  __shared__ u16 Bs[128 * 64];

  const int tid = threadIdx.x;
  const int lane = tid & 63;
  const int wave = tid >> 6;                    // 0..7
  const int wm = wave & 3, wn = wave >> 2;
  const int quad = lane >> 4, l16 = lane & 15;
  const int srow8 = lane >> 3;
  const int gchunk = (lane & 7) ^ srow8;
  const int sw = l16 & 7;

  f32x4 acc[2][4];
#pragma unroll
  for (int i = 0; i < 2; i++)
#pragma unroll
    for (int j = 0; j < 4; j++) acc[i][j] = (f32x4){0.f, 0.f, 0.f, 0.f};

  for (int k0 = 0; k0 < K; k0 += 64) {
    const int rb = wave * 16;
    async16(&A[(size_t)(tile_m + rb + srow8) * K + k0 + gchunk * 8], &As[rb * 64]);
    async16(&A[(size_t)(tile_m + rb + 8 + srow8) * K + k0 + gchunk * 8], &As[(rb + 8) * 64]);
    async16(&BT[(size_t)(tile_n + rb + srow8) * K + k0 + gchunk * 8], &Bs[rb * 64]);
    async16(&BT[(size_t)(tile_n + rb + 8 + srow8) * K + k0 + gchunk * 8], &Bs[(rb + 8) * 64]);
    __syncthreads();
#pragma unroll
    for (int ks = 0; ks < 2; ++ks) {
      short8 a[2], b[4];
#pragma unroll
      for (int i = 0; i < 2; i++)
        a[i] = *(const short8*)&As[(wm * 32 + i * 16 + l16) * 64 + ((ks * 4 + quad) ^ sw) * 8];
#pragma unroll
      for (int j = 0; j < 4; j++)
        b[j] = *(const short8*)&Bs[(wn * 64 + j * 16 + l16) * 64 + ((ks * 4 + quad) ^ sw) * 8];
#pragma unroll
      for (int i = 0; i < 2; i++)
#pragma unroll
        for (int j = 0; j < 4; j++)
          acc[i][j] = SWAP
              ? __builtin_amdgcn_mfma_f32_16x16x32_bf16(b[j], a[i], acc[i][j], 0, 0, 0)
              : __builtin_amdgcn_mfma_f32_16x16x32_bf16(a[i], b[j], acc[i][j], 0, 0, 0);
    }
    __syncthreads();
  }

  if (SWAP) {
    const float scale = (z == 0) ? 0.18033688011112042f : 1.0f;
#pragma unroll
    for (int i = 0; i < 2; i++) {
      const int s = tile_m + wm * 32 + i * 16 + l16;
      const int bb = s >> 11, sl = s & 2047;
#pragma unroll
      for (int j = 0; j < 4; j++) {
        const int nb = tile_n + wn * 64 + j * 16 + quad * 4;
        const float4 b4 = *(const float4*)&bias[nb];
        const int h = nb >> 6, e0 = nb & 63;
        ushort4 o;
        o.x = f2bf((acc[i][j][0] + b4.x) * scale);
        o.y = f2bf((acc[i][j][1] + b4.y) * scale);
        o.z = f2bf((acc[i][j][2] + b4.z) * scale);
        o.w = f2bf((acc[i][j][3] + b4.w) * scale);
        *(ushort4*)&dst[((size_t)(bb * Hn + h) * Sn + sl) * DHn + e0] = o;
      }
    }
  } else {
#pragma unroll
    for (int i = 0; i < 2; i++) {
      const int s0 = tile_m + wm * 32 + i * 16 + quad * 4;
      const int bb = s0 >> 11, sl = s0 & 2047;
#pragma unroll
      for (int j = 0; j < 4; j++) {
        const int n = tile_n + wn * 64 + j * 16 + l16;
        const int h = n >> 6, e = n & 63;
        const float bn = bias[n];
        ushort4 o;
        o.x = f2bf(acc[i][j][0] + bn);
        o.y = f2bf(acc[i][j][1] + bn);
        o.z = f2bf(acc[i][j][2] + bn);
        o.w = f2bf(acc[i][j][3] + bn);
        *(ushort4*)&dst[((size_t)(bb * Hn + h) * DHn + e) * Sn + sl] = o;
      }
    }
  }
}

// ---------------- flash attention ----------------
// grid (B*H, S/128): bh on x so the 16 q-blocks sharing one bh's K/V stream
// land on few XCDs (L2 locality: 8 bh/XCD -> 4MB K+V = one XCD L2).
// PV now via mfma_16x16x32: V staged with key-permuted columns
// (col c holds key pi(c) = g32*32 + quad*4 + (j&3) + 16*(j>>2)) so the
// concatenated 16-key P packs form the A-operand and V B-frags are direct
// b128 reads. PV MFMA count 32 -> 16 per wave-tile.
__global__ __launch_bounds__(256) void k_attn(
    const u16* __restrict__ qg, const u16* __restrict__ kg,
    const u16* __restrict__ vg, u16* __restrict__ ctx) {
  const int bh = blockIdx.x;
  const int b = bh >> 4, h = bh & 15;
  const int tid = threadIdx.x;
  const int wave = tid >> 6, lane = tid & 63;
  const int quad = lane >> 4, l16 = lane & 15;
  const int qbase = blockIdx.y * 128 + wave * 32;

  const u16* qp = qg + (size_t)bh * Sn * DHn;
  const u16* kp = kg + (size_t)bh * Sn * DHn;
  const u16* vp = vg + (size_t)bh * DHn * Sn;   // [DH][S]

  __shared__ u16 Ks[2][64 * 64];
  __shared__ u16 Vs[2][64 * LDKV];

  const int srow8 = lane >> 3;
  const int gchunk = (lane & 7) ^ srow8;
  const int sw = l16 & 7;

  const int vrow = tid >> 3;                    // 0..31
  const int vc = tid & 7;
  // permuted column bases for the two 4-key chunks of this lane's uint4
  const int vg32 = vc >> 2, vt = vc & 3;
  const int cA = vg32 * 32 + (vt & 1) * 16 + (vt >> 1) * 4;
  const int cB = cA + 8;

  short8 bq[2][2];
#pragma unroll
  for (int g2 = 0; g2 < 2; g2++) {
    bq[g2][0] = *(const short8*)&qp[(size_t)(qbase + g2 * 16 + l16) * DHn + quad * 8];
    bq[g2][1] = *(const short8*)&qp[(size_t)(qbase + g2 * 16 + l16) * DHn + 32 + quad * 8];
  }

  f32x4 octx[2][4];
#pragma unroll
  for (int g2 = 0; g2 < 2; g2++)
#pragma unroll
    for (int j = 0; j < 4; j++) octx[g2][j] = (f32x4){0.f, 0.f, 0.f, 0.f};
  float lr[2] = {0.f, 0.f};

  {
    const int rbase = wave * 16;
    async16(&kp[(size_t)(rbase + srow8) * DHn + gchunk * 8], &Ks[0][rbase * 64]);
    async16(&kp[(size_t)(rbase + 8 + srow8) * DHn + gchunk * 8], &Ks[0][(rbase + 8) * 64]);
    uint4 vv0 = *(const uint4*)&vp[(size_t)vrow * Sn + vc * 8];
    uint4 vv1 = *(const uint4*)&vp[(size_t)(32 + vrow) * Sn + vc * 8];
    *(uint2*)&Vs[0][vrow * LDKV + cA] = make_uint2(vv0.x, vv0.y);
    *(uint2*)&Vs[0][vrow * LDKV + cB] = make_uint2(vv0.z, vv0.w);
    *(uint2*)&Vs[0][(32 + vrow) * LDKV + cA] = make_uint2(vv1.x, vv1.y);
    *(uint2*)&Vs[0][(32 + vrow) * LDKV + cB] = make_uint2(vv1.z, vv1.w);
  }
  __syncthreads();

  uint4 vv0, vv1;
  for (int kt = 0; kt < Sn / 64; ++kt) {
    const int cur = kt & 1, nxt = cur ^ 1;
    const bool more = (kt + 1 < Sn / 64);
    if (more) {
      const int key1 = (kt + 1) * 64;
      const int rbase = wave * 16;
      async16(&kp[(size_t)(key1 + rbase + srow8) * DHn + gchunk * 8], &Ks[nxt][rbase * 64]);
      async16(&kp[(size_t)(key1 + rbase + 8 + srow8) * DHn + gchunk * 8], &Ks[nxt][(rbase + 8) * 64]);
      vv0 = *(const uint4*)&vp[(size_t)vrow * Sn + key1 + vc * 8];
      vv1 = *(const uint4*)&vp[(size_t)(32 + vrow) * Sn + key1 + vc * 8];
    }

    // S^T = K·Q^T, p = exp2(s); build x32 A-operands (two 16-key packs concat)
    short8 ap32[2][2];
#pragma unroll
    for (int g32 = 0; g32 < 2; g32++) {
      uint4v packs[2];
#pragma unroll
      for (int gh = 0; gh < 2; gh++) {
        const int g = g32 * 2 + gh;
        short8 ka0 = *(const short8*)&Ks[cur][(g * 16 + l16) * 64 + (quad ^ sw) * 8];
        short8 ka1 = *(const short8*)&Ks[cur][(g * 16 + l16) * 64 + ((quad + 4) ^ sw) * 8];
#pragma unroll
        for (int g2 = 0; g2 < 2; g2++) {
          f32x4 sc = (f32x4){0.f, 0.f, 0.f, 0.f};
          sc = __builtin_amdgcn_mfma_f32_16x16x32_bf16(ka0, bq[g2][0], sc, 0, 0, 0);
          sc = __builtin_amdgcn_mfma_f32_16x16x32_bf16(ka1, bq[g2][1], sc, 0, 0, 0);
          float p[4];
#pragma unroll
          for (int r = 0; r < 4; r++) p[r] = __builtin_amdgcn_exp2f(sc[r]);
          lr[g2] += (p[0] + p[1]) + (p[2] + p[3]);
          packs[g2][gh * 2] = pk2(p[0], p[1]);
          packs[g2][gh * 2 + 1] = pk2(p[2], p[3]);
        }
      }
      ap32[0][g32] = __builtin_bit_cast(short8, packs[0]);
      ap32[1][g32] = __builtin_bit_cast(short8, packs[1]);
    }

    // ctx += P·V via x32: 8 b128 V reads, 16 MFMAs
#pragma unroll
    for (int g32 = 0; g32 < 2; g32++) {
#pragma unroll
      for (int j = 0; j < 4; j++) {
        short8 vb = *(const short8*)&Vs[cur][(j * 16 + l16) * LDKV + g32 * 32 + quad * 8];
        octx[0][j] = __builtin_amdgcn_mfma_f32_16x16x32_bf16(ap32[0][g32], vb, octx[0][j], 0, 0, 0);
        octx[1][j] = __builtin_amdgcn_mfma_f32_16x16x32_bf16(ap32[1][g32], vb, octx[1][j], 0, 0, 0);
      }
    }

    if (more) {
      *(uint2*)&Vs[nxt][vrow * LDKV + cA] = make_uint2(vv0.x, vv0.y);
      *(uint2*)&Vs[nxt][vrow * LDKV + cB] = make_uint2(vv0.z, vv0.w);
      *(uint2*)&Vs[nxt][(32 + vrow) * LDKV + cA] = make_uint2(vv1.x, vv1.y);
      *(uint2*)&Vs[nxt][(32 + vrow) * LDKV + cB] = make_uint2(vv1.z, vv1.w);
    }
    __syncthreads();
  }

#pragma unroll
  for (int g2 = 0; g2 < 2; g2++) {
    lr[g2] += __shfl_xor(lr[g2], 16, 64);
    lr[g2] += __shfl_xor(lr[g2], 32, 64);
  }
  float rl[2][4];
#pragma unroll
  for (int g2 = 0; g2 < 2; g2++)
#pragma unroll
    for (int r = 0; r < 4; r++)
      rl[g2][r] = 1.0f / __shfl(lr[g2], quad * 4 + r, 64);

#pragma unroll
  for (int g2 = 0; g2 < 2; g2++)
#pragma unroll
    for (int j = 0; j < 4; j++) {
      const int n = h * DHn + j * 16 + l16;
#pragma unroll
      for (int r = 0; r < 4; r++) {
        const int s = qbase + g2 * 16 + quad * 4 + r;
        ctx[(size_t)(b * Sn + s) * Dn + n] = f2bf(octx[g2][j][r] * rl[g2][r]);
      }
    }
}

// ---------------- output projection GEMM (unchanged R6) ----------------
__global__ __launch_bounds__(512) void k_gemm_out(
    const u16* __restrict__ A, const u16* __restrict__ WoT,
    const float* __restrict__ bo, float* __restrict__ out) {
  const int tile_m = blockIdx.x * 128;
  const int tile_n = blockIdx.y * 128;
  const int K = Dn;

  __shared__ u16 As[128 * 64];
  __shared__ u16 Bs[128 * 64];

  const int tid = threadIdx.x;
  const int lane = tid & 63;
  const int wave = tid >> 6;
  const int wm = wave & 3, wn = wave >> 2;
  const int quad = lane >> 4, l16 = lane & 15;
  const int srow8 = lane >> 3;
  const int gchunk = (lane & 7) ^ srow8;
  const int sw = l16 & 7;

  f32x4 acc[2][4];
#pragma unroll
  for (int i = 0; i < 2; i++)
#pragma unroll
    for (int j = 0; j < 4; j++) acc[i][j] = (f32x4){0.f, 0.f, 0.f, 0.f};

  for (int k0 = 0; k0 < K; k0 += 64) {
    const int rb = wave * 16;
    async16(&A[(size_t)(tile_m + rb + srow8) * K + k0 + gchunk * 8], &As[rb * 64]);
    async16(&A[(size_t)(tile_m + rb + 8 + srow8) * K + k0 + gchunk * 8], &As[(rb + 8) * 64]);
    async16(&WoT[(size_t)(tile_n + rb + srow8) * K + k0 + gchunk * 8], &Bs[rb * 64]);
    async16(&WoT[(size_t)(tile_n + rb + 8 + srow8) * K + k0 + gchunk * 8], &Bs[(rb + 8) * 64]);
    __syncthreads();
#pragma unroll
    for (int ks = 0; ks < 2; ++ks) {
      short8 a[2], b[4];
#pragma unroll
      for (int i = 0; i < 2; i++)
        a[i] = *(const short8*)&As[(wm * 32 + i * 16 + l16) * 64 + ((ks * 4 + quad) ^ sw) * 8];
#pragma unroll
      for (int j = 0; j < 4; j++)
        b[j] = *(const short8*)&Bs[(wn * 64 + j * 16 + l16) * 64 + ((ks * 4 + quad) ^ sw) * 8];
#pragma unroll
      for (int i = 0; i < 2; i++)
#pragma unroll
        for (int j = 0; j < 4; j++)
          acc[i][j] = __builtin_amdgcn_mfma_f32_16x16x32_bf16(b[j], a[i], acc[i][j], 0, 0, 0);
    }
    __syncthreads();
  }

#pragma unroll
  for (int i = 0; i < 2; i++) {
    const int s = tile_m + wm * 32 + i * 16 + l16;
#pragma unroll
    for (int j = 0; j < 4; j++) {
      const int nb = tile_n + wn * 64 + j * 16 + quad * 4;
      const float4 b4 = *(const float4*)&bo[nb];
      float4 o;
      o.x = acc[i][j][0] + b4.x;
      o.y = acc[i][j][1] + b4.y;
      o.z = acc[i][j][2] + b4.z;
      o.w = acc[i][j][3] + b4.w;
      *(float4*)&out[(size_t)s * Dn + nb] = o;
    }
  }
}

extern "C" void kernel_launch(void* const* d_in, const int* in_sizes, int n_in,
                              void* d_out, int out_size, void* d_ws, size_t ws_size,
                              hipStream_t stream) {
  const float* x  = (const float*)d_in[0];
  const float* Wq = (const float*)d_in[1];
  const float* bq = (const float*)d_in[2];
  const float* Wk = (const float*)d_in[3];
  const float* bk = (const float*)d_in[4];
  const float* Wv = (const float*)d_in[5];
  const float* bv = (const float*)d_in[6];
  const float* Wo = (const float*)d_in[7];
  const float* bo = (const float*)d_in[8];
  float* out = (float*)d_out;

  // workspace carve-up (ctx aliases xb: xb dead after k_gemm_qkv) — ~75.5 MB
  char* ws = (char*)d_ws;
  u16* xb  = (u16*)ws;  ws += (size_t)Mn * Dn * 2;
  u16* WqT = (u16*)ws;  ws += (size_t)Dn * Dn * 2;
  u16* WkT = (u16*)ws;  ws += (size_t)Dn * Dn * 2;
  u16* WvT = (u16*)ws;  ws += (size_t)Dn * Dn * 2;
  u16* WoT = (u16*)ws;  ws += (size_t)Dn * Dn * 2;
  u16* qb  = (u16*)ws;  ws += (size_t)Mn * Dn * 2;
  u16* kb  = (u16*)ws;  ws += (size_t)Mn * Dn * 2;
  u16* vtb = (u16*)ws;  ws += (size_t)Mn * Dn * 2;
  u16* ctx = xb;        // alias

  k_convert_x<<<(Mn * Dn / 4) / 256, 256, 0, stream>>>((const float4*)x, (ushort4*)xb, Mn * Dn / 4);
  k_convert_w<<<1024, 256, 0, stream>>>(Wq, Wk, Wv, Wo, WqT, WkT, WvT, WoT);

  dim3 g1(Mn / 128, Dn / 128, 2);
  k_gemm_qkv<1><<<g1, 512, 0, stream>>>(xb, WqT, WkT, bq, bk, qb, kb);
  dim3 g1v(Mn / 128, Dn / 128, 1);
  k_gemm_qkv<0><<<g1v, 512, 0, stream>>>(xb, WvT, nullptr, bv, nullptr, vtb, nullptr);

  dim3 g2(Bn * Hn, Sn / 128);
  k_attn<<<g2, 256, 0, stream>>>(qb, kb, vtb, ctx);

  dim3 g3(Mn / 128, Dn / 128);
  k_gemm_out<<<g3, 512, 0, stream>>>(ctx, WoT, bo, out);
}